// Round 1
// baseline (285.874 us; speedup 1.0000x reference)
//
#include <hip/hip_runtime.h>
#include <cstdint>
#include <cstddef>

// EinsteinPINN — analytic forward-mode rewrite.
// Per sample: e = I + 0.1*(W2 h + b2);  de[m] = 0.1*W2(g.*W1[:,m]);
//             dde[p,q] = 0.1*W2(u.*W1[:,p].*W1[:,q]),  h=tanh(z), g=1-h^2, u=-2hg.
// All 15 vectors come from ONE 16x16x256 GEMM  M = W2 * G  per sample (pass 2).
// Algebra (verified): w[m,j,k] = (eta_j/2) sum_n A[j,n] (de[m,n,k]-de[n,m,k]); A=inv(e);
//   riemann[m,n,i,j] = (eta_i/2) sum_a [ Ad_m[i,a]F[n,a,j] - Ad_n[i,a]F[m,a,j]
//                                        + A[i,a](dde[n,a,m,j]-dde[m,a,n,j]) ],
//   Ad_d = -A de_d A,  F = de - de^T(first two).  Antisymmetric in (m,n): 6 pairs.
// Outputs: ricci[i,j] = eta_i sum_m A[i,m] rp[m,j], rp[m,j]=sum_{n,jj} riem[m,n,j,jj]A[jj,n]
//          riemann_out[k,l,i,j] = eta_k eta_l sum_{m<n} (A[k,m]A[l,n]-A[k,n]A[l,m]) R[(m,n)][i,j]

typedef _Float16 h2 __attribute__((ext_vector_type(2)));

#define WAVES 4
#define ITERS 8
#define GQ 5   // uint4 per G row: 4 data quads + 1 pad (80B rows -> conflict-free)

__device__ __forceinline__ float fdot2f(h2 a, h2 b, float c) {
#if __has_builtin(__builtin_amdgcn_fdot2)
  return __builtin_amdgcn_fdot2(a, b, c, false);   // v_dot2_f32_f16, fp32 accum
#else
  return c + (float)a[0] * (float)b[0] + (float)a[1] * (float)b[1];
#endif
}

__device__ __forceinline__ unsigned packh2(float lo, float hi) {
  h2 v; v[0] = (_Float16)lo; v[1] = (_Float16)hi;
  return __builtin_bit_cast(unsigned, v);
}

__global__ __launch_bounds__(256, 2) void ein_kernel(
    const float* __restrict__ x, const float* __restrict__ W1,
    const float* __restrict__ b1, const float* __restrict__ W2,
    const float* __restrict__ b2, float* __restrict__ out, int B)
{
  __shared__ __align__(16) float W1s[1024];     // [256][4]
  __shared__ float b1s[256];
  __shared__ unsigned W2s[2048];                // [n2=128][r=16], fp16 pair (2n2,2n2+1)
  __shared__ float b2s[16];
  __shared__ uint4 Gs[WAVES][128 * GQ];         // per-sample G, fp16 pairs, padded rows
  __shared__ __align__(16) float e_s[WAVES][16];
  __shared__ float de_s[WAVES][64];             // [m][i][j]
  __shared__ float dde_s[WAVES][256];           // [p][q][i][j], both sym slots
  __shared__ __align__(16) float A_s[WAVES][16];
  __shared__ float F_s[WAVES][64];              // F[m][a][k]
  __shared__ __align__(16) float U_s[WAVES][64];
  __shared__ __align__(16) float Ad_s[WAVES][64];
  __shared__ __align__(16) float R_s[WAVES][96];  // 6 pairs x 16
  __shared__ float rp_s[WAVES][16];

  const int tid  = threadIdx.x;
  const int wv   = tid >> 6;
  const int lane = tid & 63;

  // ---- stage weights ----
  for (int i = tid; i < 1024; i += 256) W1s[i] = W1[i];
  b1s[tid] = b1[tid];
  for (int i = tid; i < 2048; i += 256) {
    int n2 = i & 127, r = i >> 7;
    W2s[n2 * 16 + r] = packh2(W2[r * 256 + 2 * n2], W2[r * 256 + 2 * n2 + 1]);
  }
  if (tid < 16) b2s[tid] = b2[tid];
  __syncthreads();

  const int r16 = lane & 15;
  const int c0  = lane >> 4;
  const int dd  = lane >> 4, ii = (lane >> 2) & 3, jj = lane & 3;
  const float eta_ii = (ii == 0) ? -1.f : 1.f;
  float* out0 = out;
  float* out1 = out + (size_t)B * 16;

  for (int it = 0; it < ITERS; ++it) {
    const int s = blockIdx.x * (WAVES * ITERS) + it * WAVES + wv;
    const float4 xs = ((const float4*)x)[s];

    // ---------- pass 1: h,g,u -> G (fp16 pairs) ----------
    #pragma unroll
    for (int hh = 0; hh < 2; ++hh) {
      const int n2g = lane + hh * 64;
      float Ga[15], Gb[15];
      #pragma unroll
      for (int p = 0; p < 2; ++p) {
        float* G = p ? Gb : Ga;
        const int n = 2 * n2g + p;
        const float4 w1r = ((const float4*)W1s)[n];
        float z = b1s[n] + w1r.x * xs.x + w1r.y * xs.y + w1r.z * xs.z + w1r.w * xs.w;
        float t  = __expf(-2.f * fabsf(z));
        float r1 = __builtin_amdgcn_rcpf(1.f + t);
        float habs = (1.f - t) * r1;
        float h = (z < 0.f) ? -habs : habs;
        float g = 4.f * t * r1 * r1;      // sech^2, no cancellation
        float u = -2.f * h * g;
        G[0] = h;
        G[1] = g * w1r.x; G[2] = g * w1r.y; G[3] = g * w1r.z; G[4] = g * w1r.w;
        float u0 = u * w1r.x, u1 = u * w1r.y, u2 = u * w1r.z, u3 = u * w1r.w;
        G[5]  = u0 * w1r.x; G[6]  = u0 * w1r.y; G[7]  = u0 * w1r.z; G[8] = u0 * w1r.w;
        G[9]  = u1 * w1r.y; G[10] = u1 * w1r.z; G[11] = u1 * w1r.w;
        G[12] = u2 * w1r.z; G[13] = u2 * w1r.w;
        G[14] = u3 * w1r.w;
      }
      uint4* dst = &Gs[wv][n2g * GQ];
      dst[0] = make_uint4(packh2(Ga[0],Gb[0]),  packh2(Ga[1],Gb[1]),
                          packh2(Ga[2],Gb[2]),  packh2(Ga[3],Gb[3]));
      dst[1] = make_uint4(packh2(Ga[4],Gb[4]),  packh2(Ga[5],Gb[5]),
                          packh2(Ga[6],Gb[6]),  packh2(Ga[7],Gb[7]));
      dst[2] = make_uint4(packh2(Ga[8],Gb[8]),  packh2(Ga[9],Gb[9]),
                          packh2(Ga[10],Gb[10]),packh2(Ga[11],Gb[11]));
      dst[3] = make_uint4(packh2(Ga[12],Gb[12]),packh2(Ga[13],Gb[13]),
                          packh2(Ga[14],Gb[14]), 0u);
    }
    __syncthreads();

    // ---------- pass 2: M[r][c] = sum_n W2[r,n] G[n,c] via v_dot2 ----------
    float a0 = 0.f, a1 = 0.f, a2 = 0.f, a3 = 0.f;
    {
      const unsigned* wp = &W2s[r16];
      const uint4* gp = &Gs[wv][c0];
      #pragma unroll 8
      for (int n2 = 0; n2 < 128; ++n2) {
        h2 wr = __builtin_bit_cast(h2, wp[n2 * 16]);
        uint4 gv = gp[n2 * GQ];
        a0 = fdot2f(__builtin_bit_cast(h2, gv.x), wr, a0);
        a1 = fdot2f(__builtin_bit_cast(h2, gv.y), wr, a1);
        a2 = fdot2f(__builtin_bit_cast(h2, gv.z), wr, a2);
        a3 = fdot2f(__builtin_bit_cast(h2, gv.w), wr, a3);
      }
    }
    // writeback: cols 0=e, 1..4=de[m], 5..14=dde pairs (00,01,02,03,11,12,13,22,23,33)
    if (c0 == 0) {
      e_s[wv][r16] = 0.1f * (a0 + b2s[r16]) + (((r16 % 5) == 0) ? 1.f : 0.f);
      de_s[wv][ 0 + r16] = 0.1f * a1;
      de_s[wv][16 + r16] = 0.1f * a2;
      de_s[wv][32 + r16] = 0.1f * a3;
    } else if (c0 == 1) {
      de_s[wv][48 + r16] = 0.1f * a0;
      dde_s[wv][ 0*16 + r16] = 0.1f * a1;
      dde_s[wv][ 1*16 + r16] = 0.1f * a2; dde_s[wv][ 4*16 + r16] = 0.1f * a2;
      dde_s[wv][ 2*16 + r16] = 0.1f * a3; dde_s[wv][ 8*16 + r16] = 0.1f * a3;
    } else if (c0 == 2) {
      dde_s[wv][ 3*16 + r16] = 0.1f * a0; dde_s[wv][12*16 + r16] = 0.1f * a0;
      dde_s[wv][ 5*16 + r16] = 0.1f * a1;
      dde_s[wv][ 6*16 + r16] = 0.1f * a2; dde_s[wv][ 9*16 + r16] = 0.1f * a2;
      dde_s[wv][ 7*16 + r16] = 0.1f * a3; dde_s[wv][13*16 + r16] = 0.1f * a3;
    } else {
      dde_s[wv][10*16 + r16] = 0.1f * a0;
      dde_s[wv][11*16 + r16] = 0.1f * a1; dde_s[wv][14*16 + r16] = 0.1f * a1;
      dde_s[wv][15*16 + r16] = 0.1f * a2;
    }
    __syncthreads();

    // ---------- phase 3 ----------
    // (a) A = inv(e), all lanes redundantly (cofactor method)
    {
      float4 er0 = *(const float4*)&e_s[wv][0];
      float4 er1 = *(const float4*)&e_s[wv][4];
      float4 er2 = *(const float4*)&e_s[wv][8];
      float4 er3 = *(const float4*)&e_s[wv][12];
      float m00=er0.x,m01=er0.y,m02=er0.z,m03=er0.w;
      float m10=er1.x,m11=er1.y,m12=er1.z,m13=er1.w;
      float m20=er2.x,m21=er2.y,m22=er2.z,m23=er2.w;
      float m30=er3.x,m31=er3.y,m32=er3.z,m33=er3.w;
      float s0_=m00*m11-m01*m10, s1_=m00*m12-m02*m10, s2_=m00*m13-m03*m10;
      float s3_=m01*m12-m02*m11, s4_=m01*m13-m03*m11, s5_=m02*m13-m03*m12;
      float c5_=m22*m33-m23*m32, c4_=m21*m33-m23*m31, c3_=m21*m32-m22*m31;
      float c2_=m20*m33-m23*m30, c1_=m20*m32-m22*m30, c0_=m20*m31-m21*m30;
      float det = s0_*c5_ - s1_*c4_ + s2_*c3_ + s3_*c2_ - s4_*c1_ + s5_*c0_;
      float inv = 1.0f / det;
      float A00=( m11*c5_-m12*c4_+m13*c3_)*inv, A01=(-m01*c5_+m02*c4_-m03*c3_)*inv;
      float A02=( m31*s5_-m32*s4_+m33*s3_)*inv, A03=(-m21*s5_+m22*s4_-m23*s3_)*inv;
      float A10=(-m10*c5_+m12*c2_-m13*c1_)*inv, A11=( m00*c5_-m02*c2_+m03*c1_)*inv;
      float A12=(-m30*s5_+m32*s2_-m33*s1_)*inv, A13=( m20*s5_-m22*s2_+m23*s1_)*inv;
      float A20=( m10*c4_-m11*c2_+m13*c0_)*inv, A21=(-m00*c4_+m01*c2_-m03*c0_)*inv;
      float A22=( m30*s4_-m31*s2_+m33*s0_)*inv, A23=(-m20*s4_+m21*s2_-m23*s0_)*inv;
      float A30=(-m10*c3_+m11*c1_-m12*c0_)*inv, A31=( m00*c3_-m01*c1_+m02*c0_)*inv;
      float A32=(-m30*s3_+m31*s1_-m32*s0_)*inv, A33=( m20*s3_-m21*s1_+m22*s0_)*inv;
      if (lane == 0) {
        *(float4*)&A_s[wv][0]  = make_float4(A00,A01,A02,A03);
        *(float4*)&A_s[wv][4]  = make_float4(A10,A11,A12,A13);
        *(float4*)&A_s[wv][8]  = make_float4(A20,A21,A22,A23);
        *(float4*)&A_s[wv][12] = make_float4(A30,A31,A32,A33);
      }
    }
    __syncthreads();

    // (b) F = de - de^T(first two);  (c) U_d = A @ de_d
    F_s[wv][dd*16 + ii*4 + jj] = de_s[wv][dd*16 + ii*4 + jj] - de_s[wv][ii*16 + dd*4 + jj];
    {
      float4 Ai = *(const float4*)&A_s[wv][ii*4];
      U_s[wv][dd*16 + ii*4 + jj] =
          Ai.x * de_s[wv][dd*16 + 0 + jj] + Ai.y * de_s[wv][dd*16 + 4 + jj]
        + Ai.z * de_s[wv][dd*16 + 8 + jj] + Ai.w * de_s[wv][dd*16 + 12 + jj];
    }
    __syncthreads();

    // (d) Ad_d = -U_d @ A
    {
      float4 Ur = *(const float4*)&U_s[wv][dd*16 + ii*4];
      Ad_s[wv][dd*16 + ii*4 + jj] =
        -(Ur.x * A_s[wv][0 + jj] + Ur.y * A_s[wv][4 + jj]
        + Ur.z * A_s[wv][8 + jj] + Ur.w * A_s[wv][12 + jj]);
    }
    __syncthreads();

    // (e) R[(m,n)][i][j], 6 antisym pairs
    {
      auto riem = [&](int m, int n) -> float {
        float4 Adm = *(const float4*)&Ad_s[wv][m*16 + ii*4];
        float4 Adn = *(const float4*)&Ad_s[wv][n*16 + ii*4];
        float4 Aiv = *(const float4*)&A_s[wv][ii*4];
        float acc;
        acc  = Adm.x * F_s[wv][n*16 + 0 + jj] - Adn.x * F_s[wv][m*16 + 0 + jj]
             + Aiv.x * (dde_s[wv][(n*4+0)*16 + m*4 + jj] - dde_s[wv][(m*4+0)*16 + n*4 + jj]);
        acc += Adm.y * F_s[wv][n*16 + 4 + jj] - Adn.y * F_s[wv][m*16 + 4 + jj]
             + Aiv.y * (dde_s[wv][(n*4+1)*16 + m*4 + jj] - dde_s[wv][(m*4+1)*16 + n*4 + jj]);
        acc += Adm.z * F_s[wv][n*16 + 8 + jj] - Adn.z * F_s[wv][m*16 + 8 + jj]
             + Aiv.z * (dde_s[wv][(n*4+2)*16 + m*4 + jj] - dde_s[wv][(m*4+2)*16 + n*4 + jj]);
        acc += Adm.w * F_s[wv][n*16 + 12 + jj] - Adn.w * F_s[wv][m*16 + 12 + jj]
             + Aiv.w * (dde_s[wv][(n*4+3)*16 + m*4 + jj] - dde_s[wv][(m*4+3)*16 + n*4 + jj]);
        return 0.5f * eta_ii * acc;
      };
      int m1 = (dd < 3) ? 0 : 1;
      int n1 = (dd < 3) ? (dd + 1) : 2;        // pairs 0..3: (0,1),(0,2),(0,3),(1,2)
      R_s[wv][dd*16 + ii*4 + jj] = riem(m1, n1);
      if (dd < 2)                               // pairs 4,5: (1,3),(2,3)
        R_s[wv][(4 + dd)*16 + ii*4 + jj] = riem(dd + 1, 3);
    }
    __syncthreads();

    // (f) riemann_out[k,l,i,j] = eta_k eta_l sum_p minor_p(A;k,l) R_p[i,j]
    {
      const int kl = lane >> 2, kk = kl >> 2, ll = kl & 3, i2 = lane & 3;
      float4 akv = *(const float4*)&A_s[wv][kk*4];
      float4 alv = *(const float4*)&A_s[wv][ll*4];
      float sgn = ((kk == 0) != (ll == 0)) ? -1.f : 1.f;
      float B0 = (akv.x*alv.y - akv.y*alv.x) * sgn;
      float B1 = (akv.x*alv.z - akv.z*alv.x) * sgn;
      float B2 = (akv.x*alv.w - akv.w*alv.x) * sgn;
      float B3 = (akv.y*alv.z - akv.z*alv.y) * sgn;
      float B4 = (akv.y*alv.w - akv.w*alv.y) * sgn;
      float B5 = (akv.z*alv.w - akv.w*alv.z) * sgn;
      float4 r0 = *(const float4*)&R_s[wv][ 0 + i2*4];
      float4 r1 = *(const float4*)&R_s[wv][16 + i2*4];
      float4 r2 = *(const float4*)&R_s[wv][32 + i2*4];
      float4 r3 = *(const float4*)&R_s[wv][48 + i2*4];
      float4 r4 = *(const float4*)&R_s[wv][64 + i2*4];
      float4 r5 = *(const float4*)&R_s[wv][80 + i2*4];
      float4 o;
      o.x = B0*r0.x + B1*r1.x + B2*r2.x + B3*r3.x + B4*r4.x + B5*r5.x;
      o.y = B0*r0.y + B1*r1.y + B2*r2.y + B3*r3.y + B4*r4.y + B5*r5.y;
      o.z = B0*r0.z + B1*r1.z + B2*r2.z + B3*r3.z + B4*r4.z + B5*r5.z;
      o.w = B0*r0.w + B1*r1.w + B2*r2.w + B3*r3.w + B4*r4.w + B5*r5.w;
      ((float4*)(out1 + ((size_t)s << 8)))[kl*4 + i2] = o;
    }
    // (g1) rp[m,j'] = sum_{n,jj'} riem[m,n,j',jj'] A[jj',n]
    if (ii == 0) {
      const int m = dd, ip = jj;
      float acc = 0.f;
      #pragma unroll
      for (int n = 0; n < 4; ++n) {
        if (n != m) {
          int mm = (m < n) ? m : n;
          int nn = (m < n) ? n : m;
          int pr = mm * (7 - mm) / 2 + (nn - mm - 1);
          float sg = (m < n) ? 1.f : -1.f;
          float4 rr = *(const float4*)&R_s[wv][pr*16 + ip*4];
          acc += sg * (rr.x * A_s[wv][0 + n] + rr.y * A_s[wv][4 + n]
                     + rr.z * A_s[wv][8 + n] + rr.w * A_s[wv][12 + n]);
        }
      }
      rp_s[wv][m*4 + ip] = acc;
    }
    __syncthreads();
    // (g2) ricci[i,j] = eta_i sum_m A[i,m] rp[m,j]
    if (dd == 0) {
      float4 Ai = *(const float4*)&A_s[wv][ii*4];
      float acc = Ai.x * rp_s[wv][0 + jj] + Ai.y * rp_s[wv][4 + jj]
                + Ai.z * rp_s[wv][8 + jj] + Ai.w * rp_s[wv][12 + jj];
      out0[(size_t)s * 16 + ii*4 + jj] = eta_ii * acc;
    }
  }
}

extern "C" void kernel_launch(void* const* d_in, const int* in_sizes, int n_in,
                              void* d_out, int out_size, void* d_ws, size_t ws_size,
                              hipStream_t stream) {
  (void)n_in; (void)out_size; (void)d_ws; (void)ws_size;
  const float* x  = (const float*)d_in[0];
  const float* W1 = (const float*)d_in[1];
  const float* b1 = (const float*)d_in[2];
  const float* W2 = (const float*)d_in[3];
  const float* b2 = (const float*)d_in[4];
  float* out = (float*)d_out;
  const int B = in_sizes[0] / 4;                 // 65536
  const int nblk = B / (WAVES * ITERS);          // 2048 blocks x 256 threads
  hipLaunchKernelGGL(ein_kernel, dim3(nblk), dim3(256), 0, stream,
                     x, W1, b1, W2, b2, out, B);
}

// Round 4
// 171.090 us; speedup vs baseline: 1.6709x; 1.6709x over previous
//
#include <hip/hip_runtime.h>
#include <cstdint>
#include <cstddef>

// EinsteinPINN — analytic forward-mode rewrite, MFMA pass-2, barrier-free waves.
// Per sample: e = I + 0.1*(W2 h + b2);  de[m] = 0.1*W2(g.*W1[:,m]);
//             dde[p,q] = 0.1*W2(u.*W1[:,p].*W1[:,q]),  h=tanh(z), g=1-h^2, u=-2hg.
// All 15 columns come from ONE 16x16x256 GEMM M = W2*G per sample, computed with
// 8x v_mfma_f32_16x16x32_f16 (A = W2 fragments in registers, loop-invariant;
// B = G^T staged per-wave in LDS).  All LDS is per-wave -> NO __syncthreads;
// wave-local fences (s_waitcnt lgkmcnt(0) + sched_barrier) only.
// Algebra (verified round 1): A=inv(e); F = de - de^T(first two); Ad_d = -A de_d A;
//   riemann[m,n,i,j] = (eta_i/2) sum_a [Ad_m[i,a]F[n,a,j] - Ad_n[i,a]F[m,a,j]
//                                       + A[i,a](dde[n,a,m,j]-dde[m,a,n,j])]
//   (antisym in (m,n): 6 pairs).  Outputs are cheap A-contractions of R.

typedef _Float16 h2   __attribute__((ext_vector_type(2)));
typedef _Float16 f16x8 __attribute__((ext_vector_type(8)));
typedef float    f32x4 __attribute__((ext_vector_type(4)));

#define WAVES 4
#define ITERS 8

__device__ __forceinline__ void wfence() {
  // order all prior LDS ops before subsequent ones, wave-locally (no s_barrier)
  asm volatile("s_waitcnt lgkmcnt(0)" ::: "memory");
  __builtin_amdgcn_sched_barrier(0);
}

__device__ __forceinline__ unsigned pkrtz(float a, float b) {
#if __has_builtin(__builtin_amdgcn_cvt_pkrtz)
  return __builtin_bit_cast(unsigned, __builtin_amdgcn_cvt_pkrtz(a, b));
#else
  h2 v; v[0] = (_Float16)a; v[1] = (_Float16)b;
  return __builtin_bit_cast(unsigned, v);
#endif
}

__global__ __launch_bounds__(256, 3) void ein_kernel(
    const float* __restrict__ x, const float* __restrict__ W1,
    const float* __restrict__ b1, const float* __restrict__ W2,
    const float* __restrict__ b2, float* __restrict__ out, int B)
{
  // ---- per-wave LDS (49152 B total -> 3 blocks/CU) ----
  __shared__ __align__(16) _Float16 Gt[WAVES][16][264]; // G^T: [c][n], 264 = 256 + 8 pad
  __shared__ __align__(16) float Qs[WAVES][320];        // M cols, stride 20: c*20 + r
  __shared__ __align__(16) float dde2[WAVES][320];      // [p*4+q][r], stride 20, sym-dup
  __shared__ __align__(16) float A_s[WAVES][16];
  __shared__ float F_s[WAVES][64];
  __shared__ float U_s[WAVES][64];
  __shared__ float Ad_s[WAVES][64];
  __shared__ __align__(16) float R_s[WAVES][96];        // 6 pairs x 16
  __shared__ float rp_s[WAVES][16];

  const int tid  = threadIdx.x;
  const int wv   = tid >> 6;
  const int lane = tid & 63;
  const int l15  = lane & 15;
  const int hb   = lane >> 4;
  const int dd = lane >> 4, ii = (lane >> 2) & 3, jj = lane & 3;
  const float eta_ii = (ii == 0) ? -1.f : 1.f;

  // ---- loop-invariant register state ----
  // W1 rows + b1 for this lane's 4 neurons: 2*lane, 2*lane+1, 2*lane+128, 2*lane+129
  const float4 w1A = ((const float4*)W1)[2*lane];
  const float4 w1B = ((const float4*)W1)[2*lane + 1];
  const float4 w1C = ((const float4*)W1)[2*lane + 128];
  const float4 w1D = ((const float4*)W1)[2*lane + 129];
  const float b1A = b1[2*lane],       b1B = b1[2*lane + 1];
  const float b1C = b1[2*lane + 128], b1D = b1[2*lane + 129];
  // MFMA A-fragments: lane holds W2[row=l15][k = cc*32 + hb*8 + j], j=0..7
  f16x8 afr[8];
  #pragma unroll
  for (int cc = 0; cc < 8; ++cc) {
    const float* p = W2 + l15*256 + cc*32 + hb*8;
    float4 u0 = ((const float4*)p)[0];
    float4 u1 = ((const float4*)p)[1];
    f16x8 a;
    a[0]=(_Float16)u0.x; a[1]=(_Float16)u0.y; a[2]=(_Float16)u0.z; a[3]=(_Float16)u0.w;
    a[4]=(_Float16)u1.x; a[5]=(_Float16)u1.y; a[6]=(_Float16)u1.z; a[7]=(_Float16)u1.w;
    afr[cc] = a;
  }
  const float eb0 = b2[4*hb+0], eb1 = b2[4*hb+1], eb2 = b2[4*hb+2], eb3 = b2[4*hb+3];

  float* out0 = out;
  float* out1 = out + (size_t)B * 16;

  // per-neuron activation pieces: h, g*w (4), u*w (4)
  auto neuron = [](const float4& w, float b, const float4& xs,
                   float& h, float4& gw4, float4& uw4) {
    float z = b + w.x*xs.x + w.y*xs.y + w.z*xs.z + w.w*xs.w;
    float t  = __expf(-2.f * fabsf(z));
    float r1 = __builtin_amdgcn_rcpf(1.f + t);
    float habs = (1.f - t) * r1;
    h = (z < 0.f) ? -habs : habs;
    float g = 4.f * t * r1 * r1;         // sech^2, no cancellation
    float u = -2.f * h * g;
    gw4 = make_float4(g*w.x, g*w.y, g*w.z, g*w.w);
    uw4 = make_float4(u*w.x, u*w.y, u*w.z, u*w.w);
  };

  const int sbase = blockIdx.x * (WAVES * ITERS);
  float4 xs = ((const float4*)x)[sbase + wv];

  for (int it = 0; it < ITERS; ++it) {
    const int s = sbase + it * WAVES + wv;
    const float4 xc = xs;
    if (it + 1 < ITERS) xs = ((const float4*)x)[sbase + (it + 1) * WAVES + wv];

    // ---------- pass 1: G^T staging (f16 pairs, stride-1 writes = conflict-free) ----
    unsigned* gwp = (unsigned*)&Gt[wv][0][2*lane];   // base; row stride 132 u32
    {
      float hA, hB; float4 gA, gB, uA, uB;
      neuron(w1A, b1A, xc, hA, gA, uA);
      neuron(w1B, b1B, xc, hB, gB, uB);
      gwp[0*132] = pkrtz(hA, hB);
      gwp[1*132] = pkrtz(gA.x, gB.x);  gwp[2*132] = pkrtz(gA.y, gB.y);
      gwp[3*132] = pkrtz(gA.z, gB.z);  gwp[4*132] = pkrtz(gA.w, gB.w);
      gwp[5*132]  = pkrtz(uA.x*w1A.x, uB.x*w1B.x);
      gwp[6*132]  = pkrtz(uA.x*w1A.y, uB.x*w1B.y);
      gwp[7*132]  = pkrtz(uA.x*w1A.z, uB.x*w1B.z);
      gwp[8*132]  = pkrtz(uA.x*w1A.w, uB.x*w1B.w);
      gwp[9*132]  = pkrtz(uA.y*w1A.y, uB.y*w1B.y);
      gwp[10*132] = pkrtz(uA.y*w1A.z, uB.y*w1B.z);
      gwp[11*132] = pkrtz(uA.y*w1A.w, uB.y*w1B.w);
      gwp[12*132] = pkrtz(uA.z*w1A.z, uB.z*w1B.z);
      gwp[13*132] = pkrtz(uA.z*w1A.w, uB.z*w1B.w);
      gwp[14*132] = pkrtz(uA.w*w1A.w, uB.w*w1B.w);
    }
    {
      float hA, hB; float4 gA, gB, uA, uB;
      neuron(w1C, b1C, xc, hA, gA, uA);
      neuron(w1D, b1D, xc, hB, gB, uB);
      gwp[0*132+64] = pkrtz(hA, hB);
      gwp[1*132+64] = pkrtz(gA.x, gB.x);  gwp[2*132+64] = pkrtz(gA.y, gB.y);
      gwp[3*132+64] = pkrtz(gA.z, gB.z);  gwp[4*132+64] = pkrtz(gA.w, gB.w);
      gwp[5*132+64]  = pkrtz(uA.x*w1C.x, uB.x*w1D.x);
      gwp[6*132+64]  = pkrtz(uA.x*w1C.y, uB.x*w1D.y);
      gwp[7*132+64]  = pkrtz(uA.x*w1C.z, uB.x*w1D.z);
      gwp[8*132+64]  = pkrtz(uA.x*w1C.w, uB.x*w1D.w);
      gwp[9*132+64]  = pkrtz(uA.y*w1C.y, uB.y*w1D.y);
      gwp[10*132+64] = pkrtz(uA.y*w1C.z, uB.y*w1D.z);
      gwp[11*132+64] = pkrtz(uA.y*w1C.w, uB.y*w1D.w);
      gwp[12*132+64] = pkrtz(uA.z*w1C.z, uB.z*w1D.z);
      gwp[13*132+64] = pkrtz(uA.z*w1C.w, uB.z*w1D.w);
      gwp[14*132+64] = pkrtz(uA.w*w1C.w, uB.w*w1D.w);
    }
    wfence();

    // ---------- pass 2: M = W2*G via 8x mfma_f32_16x16x32_f16 ----------
    // B-frag: lane holds G[k = cc*32 + hb*8 + j][col=l15] = Gt[l15][cc*32 + hb*8 + j]
    f32x4 acc = {0.f, 0.f, 0.f, 0.f};
    {
      const f16x8* gp = (const f16x8*)&Gt[wv][l15][hb*8];
      #pragma unroll
      for (int cc = 0; cc < 8; ++cc) {
        f16x8 bfr = gp[cc * 4];          // +cc*32 f16
        acc = __builtin_amdgcn_mfma_f32_16x16x32_f16(afr[cc], bfr, acc, 0, 0, 0);
      }
    }
    // ---------- writeback: lane holds M[r=4*hb+q][c=l15] in acc[q] ----------
    {
      float v0 = 0.1f*acc[0], v1 = 0.1f*acc[1], v2 = 0.1f*acc[2], v3 = 0.1f*acc[3];
      if (l15 == 0) {   // e column: + 0.1*b2 + I   (r=4hb+q -> i=hb, j=q)
        v0 += 0.1f*eb0 + ((hb == 0) ? 1.f : 0.f);
        v1 += 0.1f*eb1 + ((hb == 1) ? 1.f : 0.f);
        v2 += 0.1f*eb2 + ((hb == 2) ? 1.f : 0.f);
        v3 += 0.1f*eb3 + ((hb == 3) ? 1.f : 0.f);
      }
      float4 v4 = make_float4(v0, v1, v2, v3);
      *(float4*)&Qs[wv][l15*20 + hb*4] = v4;
      if (l15 >= 5 && l15 <= 14) {       // dde columns -> [p][q] grid with sym dup
        int t = l15 - 5;                  // 0..9, pairs (0,0),(0,1),(0,2),(0,3),(1,1),...
        int p = (t >= 9) ? 3 : (t >= 7) ? 2 : (t >= 4) ? 1 : 0;
        int q = t - ((p * (7 - p)) >> 1);
        *(float4*)&dde2[wv][(p*4 + q)*20 + hb*4] = v4;
        if (p != q) *(float4*)&dde2[wv][(q*4 + p)*20 + hb*4] = v4;
      }
    }
    wfence();

    // ---------- phase 3 ----------
    // (a) A = inv(e), all lanes redundant (cofactor)
    {
      float4 er0 = *(const float4*)&Qs[wv][0];
      float4 er1 = *(const float4*)&Qs[wv][4];
      float4 er2 = *(const float4*)&Qs[wv][8];
      float4 er3 = *(const float4*)&Qs[wv][12];
      float m00=er0.x,m01=er0.y,m02=er0.z,m03=er0.w;
      float m10=er1.x,m11=er1.y,m12=er1.z,m13=er1.w;
      float m20=er2.x,m21=er2.y,m22=er2.z,m23=er2.w;
      float m30=er3.x,m31=er3.y,m32=er3.z,m33=er3.w;
      float s0_=m00*m11-m01*m10, s1_=m00*m12-m02*m10, s2_=m00*m13-m03*m10;
      float s3_=m01*m12-m02*m11, s4_=m01*m13-m03*m11, s5_=m02*m13-m03*m12;
      float c5_=m22*m33-m23*m32, c4_=m21*m33-m23*m31, c3_=m21*m32-m22*m31;
      float c2_=m20*m33-m23*m30, c1_=m20*m32-m22*m30, c0_=m20*m31-m21*m30;
      float det = s0_*c5_ - s1_*c4_ + s2_*c3_ + s3_*c2_ - s4_*c1_ + s5_*c0_;
      float inv = 1.0f / det;
      if (lane == 0) {
        *(float4*)&A_s[wv][0]  = make_float4(( m11*c5_-m12*c4_+m13*c3_)*inv,
                                             (-m01*c5_+m02*c4_-m03*c3_)*inv,
                                             ( m31*s5_-m32*s4_+m33*s3_)*inv,
                                             (-m21*s5_+m22*s4_-m23*s3_)*inv);
        *(float4*)&A_s[wv][4]  = make_float4((-m10*c5_+m12*c2_-m13*c1_)*inv,
                                             ( m00*c5_-m02*c2_+m03*c1_)*inv,
                                             (-m30*s5_+m32*s2_-m33*s1_)*inv,
                                             ( m20*s5_-m22*s2_+m23*s1_)*inv);
        *(float4*)&A_s[wv][8]  = make_float4(( m10*c4_-m11*c2_+m13*c0_)*inv,
                                             (-m00*c4_+m01*c2_-m03*c0_)*inv,
                                             ( m30*s4_-m31*s2_+m33*s0_)*inv,
                                             (-m20*s4_+m21*s2_-m23*s0_)*inv);
        *(float4*)&A_s[wv][12] = make_float4((-m10*c3_+m11*c1_-m12*c0_)*inv,
                                             ( m00*c3_-m01*c1_+m02*c0_)*inv,
                                             (-m30*s3_+m31*s1_-m32*s0_)*inv,
                                             ( m20*s3_-m21*s1_+m22*s0_)*inv);
      }
    }
    wfence();

    // (b) F = de - de^T(first two);  (c) U_d = A @ de_d    [de[m][r] = Qs[(1+m)*20+r]]
    F_s[wv][dd*16 + ii*4 + jj] = Qs[wv][(1+dd)*20 + ii*4 + jj]
                               - Qs[wv][(1+ii)*20 + dd*4 + jj];
    {
      float4 Ai = *(const float4*)&A_s[wv][ii*4];
      U_s[wv][dd*16 + ii*4 + jj] =
          Ai.x * Qs[wv][(1+dd)*20 +  0 + jj] + Ai.y * Qs[wv][(1+dd)*20 +  4 + jj]
        + Ai.z * Qs[wv][(1+dd)*20 +  8 + jj] + Ai.w * Qs[wv][(1+dd)*20 + 12 + jj];
    }
    wfence();

    // (d) Ad_d = -U_d @ A
    {
      float4 Ur = *(const float4*)&U_s[wv][dd*16 + ii*4];
      Ad_s[wv][dd*16 + ii*4 + jj] =
        -(Ur.x * A_s[wv][0 + jj] + Ur.y * A_s[wv][4 + jj]
        + Ur.z * A_s[wv][8 + jj] + Ur.w * A_s[wv][12 + jj]);
    }
    wfence();

    // (e) R[(m,n)][i][j], 6 antisym pairs   [dde[p][q][r] = dde2[(p*4+q)*20+r]]
    {
      auto riem = [&](int m, int n) -> float {
        float4 Adm = *(const float4*)&Ad_s[wv][m*16 + ii*4];
        float4 Adn = *(const float4*)&Ad_s[wv][n*16 + ii*4];
        float4 Aiv = *(const float4*)&A_s[wv][ii*4];
        float a;
        a  = Adm.x * F_s[wv][n*16 +  0 + jj] - Adn.x * F_s[wv][m*16 +  0 + jj]
           + Aiv.x * (dde2[wv][(n*4+0)*20 + m*4 + jj] - dde2[wv][(m*4+0)*20 + n*4 + jj]);
        a += Adm.y * F_s[wv][n*16 +  4 + jj] - Adn.y * F_s[wv][m*16 +  4 + jj]
           + Aiv.y * (dde2[wv][(n*4+1)*20 + m*4 + jj] - dde2[wv][(m*4+1)*20 + n*4 + jj]);
        a += Adm.z * F_s[wv][n*16 +  8 + jj] - Adn.z * F_s[wv][m*16 +  8 + jj]
           + Aiv.z * (dde2[wv][(n*4+2)*20 + m*4 + jj] - dde2[wv][(m*4+2)*20 + n*4 + jj]);
        a += Adm.w * F_s[wv][n*16 + 12 + jj] - Adn.w * F_s[wv][m*16 + 12 + jj]
           + Aiv.w * (dde2[wv][(n*4+3)*20 + m*4 + jj] - dde2[wv][(m*4+3)*20 + n*4 + jj]);
        return 0.5f * eta_ii * a;
      };
      int m1 = (dd < 3) ? 0 : 1;
      int n1 = (dd < 3) ? (dd + 1) : 2;          // pairs 0..3: (0,1),(0,2),(0,3),(1,2)
      R_s[wv][dd*16 + ii*4 + jj] = riem(m1, n1);
      if (dd < 2)                                 // pairs 4,5: (1,3),(2,3)
        R_s[wv][(4 + dd)*16 + ii*4 + jj] = riem(dd + 1, 3);
    }
    wfence();

    // (f) riemann_out[k,l,i,j] = eta_k eta_l sum_p minor_p(A;k,l) R_p[i,j]
    {
      const int kl = lane >> 2, kk = kl >> 2, ll = kl & 3, i2 = lane & 3;
      float4 akv = *(const float4*)&A_s[wv][kk*4];
      float4 alv = *(const float4*)&A_s[wv][ll*4];
      float sgn = ((kk == 0) != (ll == 0)) ? -1.f : 1.f;
      float B0 = (akv.x*alv.y - akv.y*alv.x) * sgn;
      float B1 = (akv.x*alv.z - akv.z*alv.x) * sgn;
      float B2 = (akv.x*alv.w - akv.w*alv.x) * sgn;
      float B3 = (akv.y*alv.z - akv.z*alv.y) * sgn;
      float B4 = (akv.y*alv.w - akv.w*alv.y) * sgn;
      float B5 = (akv.z*alv.w - akv.w*alv.z) * sgn;
      float4 r0 = *(const float4*)&R_s[wv][ 0 + i2*4];
      float4 r1 = *(const float4*)&R_s[wv][16 + i2*4];
      float4 r2 = *(const float4*)&R_s[wv][32 + i2*4];
      float4 r3 = *(const float4*)&R_s[wv][48 + i2*4];
      float4 r4 = *(const float4*)&R_s[wv][64 + i2*4];
      float4 r5 = *(const float4*)&R_s[wv][80 + i2*4];
      float4 o;
      o.x = B0*r0.x + B1*r1.x + B2*r2.x + B3*r3.x + B4*r4.x + B5*r5.x;
      o.y = B0*r0.y + B1*r1.y + B2*r2.y + B3*r3.y + B4*r4.y + B5*r5.y;
      o.z = B0*r0.z + B1*r1.z + B2*r2.z + B3*r3.z + B4*r4.z + B5*r5.z;
      o.w = B0*r0.w + B1*r1.w + B2*r2.w + B3*r3.w + B4*r4.w + B5*r5.w;
      ((float4*)(out1 + ((size_t)s << 8)))[kl*4 + i2] = o;
    }
    // (g1) rp[m,j'] = sum over n of sgn * R[(m,n)] col-contraction with A
    if (ii == 0) {
      const int m = dd, ip = jj;
      float a = 0.f;
      #pragma unroll
      for (int n = 0; n < 4; ++n) {
        if (n != m) {
          int mm = (m < n) ? m : n;
          int nn = (m < n) ? n : m;
          int pr = mm * (7 - mm) / 2 + (nn - mm - 1);
          float sg = (m < n) ? 1.f : -1.f;
          float4 rr = *(const float4*)&R_s[wv][pr*16 + ip*4];
          a += sg * (rr.x * A_s[wv][0 + n] + rr.y * A_s[wv][4 + n]
                   + rr.z * A_s[wv][8 + n] + rr.w * A_s[wv][12 + n]);
        }
      }
      rp_s[wv][m*4 + ip] = a;
    }
    wfence();
    // (g2) ricci[i,j] = eta_i sum_m A[i,m] rp[m,j]
    if (dd == 0) {
      float4 Ai = *(const float4*)&A_s[wv][ii*4];
      float a = Ai.x * rp_s[wv][0 + jj] + Ai.y * rp_s[wv][4 + jj]
              + Ai.z * rp_s[wv][8 + jj] + Ai.w * rp_s[wv][12 + jj];
      out0[(size_t)s * 16 + ii*4 + jj] = eta_ii * a;
    }
  }
}

extern "C" void kernel_launch(void* const* d_in, const int* in_sizes, int n_in,
                              void* d_out, int out_size, void* d_ws, size_t ws_size,
                              hipStream_t stream) {
  (void)n_in; (void)out_size; (void)d_ws; (void)ws_size;
  const float* x  = (const float*)d_in[0];
  const float* W1 = (const float*)d_in[1];
  const float* b1 = (const float*)d_in[2];
  const float* W2 = (const float*)d_in[3];
  const float* b2 = (const float*)d_in[4];
  float* out = (float*)d_out;
  const int B = in_sizes[0] / 4;                 // 65536
  const int nblk = B / (WAVES * ITERS);          // 2048 blocks x 256 threads
  hipLaunchKernelGGL(ein_kernel, dim3(nblk), dim3(256), 0, stream,
                     x, W1, b1, W2, b2, out, B);
}